// Round 11
// baseline (188.557 us; speedup 1.0000x reference)
//
#include <hip/hip_runtime.h>
#include <hip/hip_bf16.h>
#include <stdint.h>

// VQ-VAE vector quantizer forward, MI355X (gfx950).
// z: [32,256,32,32] fp32 (NCHW), E: [1024,256] fp32.
// score(n,k) = 0.5*||e_k||^2 - <f_n,e_k>  (argmin-equivalent to d2)
// dots via bf16 MFMA 16x16x32 fp32-accum; gather exact fp32.
//
// R16: loop ~31us is invariant under LDS-halving/barrier-halving/counted-
// vmcnt/wave-doubling -- every per-resource theory dead. The untested
// mechanism: PHASE SKEW across independent barrier domains (R9's extra
// waves shared one barrier = lockstep; R8 had 2 domains but doubled
// per-CU staging). This round: grid 512 = (row-tile, code-HALF). Each
// block stages only its 256KB half-codebook -> per-CU staged bytes
// unchanged (512KB), per-CU MFMA/LDS/VALU unchanged, LDS 67KB/block x2
// fits. Two co-resident blocks' drains/A-prep overlap each other's MFMA.
// Winners merge via atomicMin on packed u64 (same compare as the old
// pairLds merge -> bit-identical winners, order-independent). Loss +
// scalars move to k_epi (score from packed hi, ||z||^2 from nrmG).

typedef short v8s __attribute__((ext_vector_type(8)));
typedef float v4f __attribute__((ext_vector_type(4)));

__device__ inline unsigned short f2bf(float f) {  // RNE fp32->bf16
    uint32_t u = __float_as_uint(f);
    return (unsigned short)((u + 0x7fffu + ((u >> 16) & 1u)) >> 16);
}

// ---- Kernel 1: E -> SWIZZLED Ebf bf16 + nE + idxPk/accum/done init ---------
// Unit for (k, dc, g): U = (k>>4)*512 + dc*64 + g*16 + (k&15),
// holding elems d = dc*32 + g*8 .. +8. Coalesced 16B stores.
__global__ __launch_bounds__(256) void k_prep_e(const float* __restrict__ E,
                                                v8s* __restrict__ Esw,
                                                float* __restrict__ nE,
                                                unsigned long long* __restrict__ idxPk,
                                                float* __restrict__ accum,
                                                unsigned* __restrict__ done) {
    __shared__ float Ef[16][264];
    int q = blockIdx.x, tid = threadIdx.x;
    const float4* Ein = (const float4*)(E + ((size_t)q << 12));
#pragma unroll
    for (int i = 0; i < 4; i++) {
        int f4 = i * 256 + tid;
        int row = f4 >> 6, c4 = (f4 & 63) << 2;
        *(float4*)&Ef[row][c4] = Ein[f4];
    }
    {   // winner-table init: 2 u64 per thread, 64*256*2 = 32768
        int u = (q << 8) + tid;
        idxPk[(size_t)(u << 1)]     = ~0ull;
        idxPk[(size_t)(u << 1) + 1] = ~0ull;
    }
    __syncthreads();
    {
        int c = tid >> 4, l = tid & 15;
        float s = 0.f;
#pragma unroll
        for (int j = 0; j < 16; j++) { float v = Ef[c][l + 16 * j]; s += v * v; }
#pragma unroll
        for (int off = 1; off < 16; off <<= 1) s += __shfl_xor(s, off);
        if (l == 0) nE[q * 16 + c] = 0.5f * s;
    }
#pragma unroll
    for (int i = 0; i < 2; i++) {
        int u = tid + i * 256;
        int um = u & 15, ug = (u >> 4) & 3, udc = (u >> 6) & 7;
        int d0 = udc * 32 + ug * 8;
        union { v8s v; unsigned short s[8]; } pk;
#pragma unroll
        for (int e = 0; e < 8; e++) pk.s[e] = f2bf(Ef[um][d0 + e]);
        Esw[((size_t)q << 9) + u] = pk.v;
    }
    if (q == 0 && tid == 0) { accum[0] = 0.f; done[0] = 0u; }
}

// ---- Kernel 2: transpose+GEMM+argmin over a code-HALF; atomicMin winners ----
__global__ __launch_bounds__(512, 4) void k_main(
        const v8s* __restrict__ Esw,
        const float* __restrict__ nE,
        const float* __restrict__ z,
        unsigned long long* __restrict__ idxPk,
        float* __restrict__ nrmG) {
    __shared__ v8s B[2][2048];      // 2 x 32 KB dbuf; A-tile (64 KB) overlays both
    __shared__ float nEl[512];

    int tid = threadIdx.x;
    int lane = tid & 63, w = tid >> 6;         // 8 waves
    int g = lane >> 4, m = lane & 15;          // MFMA lane coords
    int r_tile = blockIdx.x >> 1, h = blockIdx.x & 1;
    int R0 = r_tile << 7;                      // 128 rows/tile
    int b = R0 >> 10, hw0 = R0 & 1023;

    // ---- A-prep: z[b][0..256][hw0..hw0+128] -> swizzled bf16 tile @B -------
    // Thread (q=tid&31, dblk=tid>>5) loads 16 d-rows x float4 at hw quad 4q,
    // repacks to 8 v8s (4 rows x 2 slots). Swizzle slot^((row^row>>2)&7)
    // spreads both writes and fragment reads across all 8 bank-quads.
    {
        int q = tid & 31, dblk = tid >> 5;     // hw = hw0+4q, d base = dblk*16
        const float* zp = z + ((size_t)b << 18) + hw0 + (q << 2);
#pragma unroll
        for (int s = 0; s < 2; s++) {
            float4 L[8];
#pragma unroll
            for (int j = 0; j < 8; j++)
                L[j] = *(const float4*)(zp + (size_t)(((dblk << 4) + (s << 3) + j) << 10));
            const float* Lf = (const float*)L;
            int slot = (dblk << 1) + s;
#pragma unroll
            for (int c = 0; c < 4; c++) {
                union { v8s v; unsigned short u[8]; } pk;
#pragma unroll
                for (int j = 0; j < 8; j++) pk.u[j] = f2bf(Lf[j * 4 + c]);
                int row = (q << 2) + c;
                int sw = slot ^ ((row ^ (row >> 2)) & 7);
                *(v8s*)((char*)&B[0][0] + (row << 9) + (sw << 4)) = pk.v;
            }
        }
    }
    nEl[tid & 511] = nE[(h << 9) + (tid & 511)];
    __syncthreads();                           // A-tile + nEl resident

    // A frags: 16 rows/wave; row norm from the same bf16 values (h==0 writes).
    v8s a[8];
    {
        int row = (w << 4) + m;
        int f = (row ^ (row >> 2)) & 7;
#pragma unroll
        for (int dc = 0; dc < 8; dc++) {
            int sw = ((dc << 2) + g) ^ f;
            a[dc] = *(const v8s*)((const char*)&B[0][0] + (row << 9) + (sw << 4));
        }
        if (h == 0) {
            float nrm = 0.f;
#pragma unroll
            for (int dc = 0; dc < 8; dc++) {
                union { v8s v; unsigned short u[8]; } un; un.v = a[dc];
#pragma unroll
                for (int j = 0; j < 8; j++) {
                    float v = __uint_as_float((uint32_t)un.u[j] << 16);
                    nrm = fmaf(v, v, nrm);
                }
            }
            nrm += __shfl_xor(nrm, 16);        // reduce over g: full ||z_row||^2
            nrm += __shfl_xor(nrm, 32);
            if (g == 0) nrmG[R0 + row] = nrm;
        }
    }
    __syncthreads();                           // A consumed; B free for staging

    // staging: this half's chunk = 2048 v8s (32 KB); thread stages j*512+tid
#define STAGE(ch, buf)                                                        \
    {                                                                         \
        _Pragma("unroll")                                                     \
        for (int j = 0; j < 4; j++) {                                         \
            __builtin_amdgcn_global_load_lds(                                 \
                (const __attribute__((address_space(1))) void*)               \
                    (Esw + ((size_t)(h) << 14) + ((size_t)(ch) << 11)         \
                         + (j << 9) + (w << 6) + lane),                       \
                (__attribute__((address_space(3))) void*)                     \
                    &B[buf][(j << 9) + (w << 6)],                             \
                16, 0, 0);                                                    \
        }                                                                     \
    }

    float best[4]; int bidx[4];
#pragma unroll
    for (int r = 0; r < 4; r++) { best[r] = 3.4e38f; bidx[r] = 0; }

    STAGE(0, 0);
#pragma unroll 2
    for (int ct = 0; ct < 8; ct++) {
        int cur = ct & 1;                      // static after unroll 2
        __syncthreads();                       // chunk ct resident; reads done
        if (ct < 7) STAGE(ct + 1, cur ^ 1);
        float ne[4];
#pragma unroll
        for (int t = 0; t < 4; t++) ne[t] = nEl[(ct << 6) + (t << 4) + m];
        v4f acc[4];
#pragma unroll
        for (int t = 0; t < 4; t++) acc[t] = (v4f){0.f, 0.f, 0.f, 0.f};
#pragma unroll
        for (int dc = 0; dc < 8; dc++) {       // 4 indep chains/wave
#pragma unroll
            for (int t = 0; t < 4; t++) {
                v8s bf = B[cur][t * 512 + dc * 64 + g * 16 + m];
                acc[t] = __builtin_amdgcn_mfma_f32_16x16x32_bf16(a[dc], bf, acc[t], 0, 0, 0);
            }
        }
#pragma unroll
        for (int t = 0; t < 4; t++) {          // ascending code: tie -> low idx
            int code = (h << 9) + (ct << 6) + (t << 4) + m;
#pragma unroll
            for (int r = 0; r < 4; r++) {
                float s0 = ne[t] - acc[t][r];
                if (s0 < best[r]) { best[r] = s0; bidx[r] = code; }
            }
        }
    }

    // winner reduce over 16 code-columns; merge across halves via atomicMin
    // (u64 pack: min => low score, then low code -- same compare as before).
#pragma unroll
    for (int r = 0; r < 4; r++) {
        uint32_t sb = __float_as_uint(best[r]);
        sb = (sb & 0x80000000u) ? ~sb : (sb | 0x80000000u);
        unsigned long long pk = ((unsigned long long)sb << 32) | (uint32_t)bidx[r];
#pragma unroll
        for (int off = 1; off < 16; off <<= 1) {
            unsigned long long o = __shfl_xor(pk, off);
            if (o < pk) pk = o;
        }
        if (m == 0) {                          // C/D row = g*4 + r
            int row = (w << 4) + (g << 2) + r;
            atomicMin(&idxPk[R0 + row], pk);
        }
    }
#undef STAGE
}

// ---- Kernel 3: epilogue gather + NCHW write + loss + scalars ----------------
// Block j owns (b = j>>6, d-quad d0 = (j&63)*4). Thread t: hw quad 4t ->
// 4 packed winners, 4x16B E-gathers (L2), register 4x4 transpose, 4
// coalesced float4 row-stores. Blocks with (j&63)==0 also fold the loss:
// ||e*-z||^2 = 2*s* + ||z||^2 from the packed score + nrmG. Last block
// (done counter) writes the 3 scalars.
__global__ __launch_bounds__(256) void k_epi(const unsigned long long* __restrict__ idxPk,
                                             const float* __restrict__ nrmG,
                                             const float* __restrict__ E,
                                             float* __restrict__ accum,
                                             unsigned* __restrict__ done,
                                             float* __restrict__ out) {
    int j = blockIdx.x, t = threadIdx.x;
    int b = j >> 6, d0 = (j & 63) << 2;
    const unsigned long long* pkRow = idxPk + (b << 10) + (t << 2);
    unsigned long long p0 = pkRow[0], p1 = pkRow[1], p2 = pkRow[2], p3 = pkRow[3];
    float4 e0 = *(const float4*)(E + ((size_t)(uint32_t)p0 << 8) + d0);
    float4 e1 = *(const float4*)(E + ((size_t)(uint32_t)p1 << 8) + d0);
    float4 e2 = *(const float4*)(E + ((size_t)(uint32_t)p2 << 8) + d0);
    float4 e3 = *(const float4*)(E + ((size_t)(uint32_t)p3 << 8) + d0);
    const float* q0 = &e0.x; const float* q1 = &e1.x;
    const float* q2 = &e2.x; const float* q3 = &e3.x;
    float* ob = out + ((size_t)b << 18) + ((size_t)d0 << 10) + (t << 2);
#pragma unroll
    for (int i = 0; i < 4; i++) {
        float4 v; v.x = q0[i]; v.y = q1[i]; v.z = q2[i]; v.w = q3[i];
        *(float4*)(ob + (size_t)i * 1024) = v;
    }
    if ((j & 63) == 0) {                       // loss for this batch's 1024 rows
        float ls = 0.f;
        const unsigned long long* pp[4] = {&p0, &p1, &p2, &p3};
#pragma unroll
        for (int i = 0; i < 4; i++) {
            uint32_t sc = (uint32_t)(*pp[i] >> 32);
            float s = __uint_as_float((sc & 0x80000000u) ? (sc & 0x7fffffffu) : ~sc);
            ls += 2.0f * s + nrmG[(b << 10) + (t << 2) + i];
        }
#pragma unroll
        for (int off = 1; off < 64; off <<= 1) ls += __shfl_xor(ls, off);
        __shared__ float w4[4];
        if ((t & 63) == 0) w4[t >> 6] = ls;
        __syncthreads();
        if (t == 0) atomicAdd(accum, w4[0] + w4[1] + w4[2] + w4[3]);
    }
    if (t == 0) {                              // last of 2048 blocks -> scalars
        __threadfence();
        unsigned old = atomicAdd(done, 1u);
        if (old == 2047u) {
            float s = atomicAdd(accum, 0.f) * (1.0f / 8388608.0f);
            out[8388608] = 1.25f * s;
            out[8388609] = s;
            out[8388610] = s;
        }
    }
}

extern "C" void kernel_launch(void* const* d_in, const int* in_sizes, int n_in,
                              void* d_out, int out_size, void* d_ws, size_t ws_size,
                              hipStream_t stream) {
    const float* z = (const float*)d_in[0];
    const float* E = (const float*)d_in[1];
    char* ws = (char*)d_ws;
    v8s*                Esw   = (v8s*)(ws);                 // 524,288 B
    float*              nE    = (float*)(ws + 524288);      //   4,096 B
    float*              accum = (float*)(ws + 528384);      //       4 B
    unsigned*           done  = (unsigned*)(ws + 528388);   //       4 B
    float*              nrmG  = (float*)(ws + 528392);      // 131,072 B
    unsigned long long* idxPk = (unsigned long long*)(ws + 659464);  // 262,144 B
    float* out = (float*)d_out;

    hipLaunchKernelGGL(k_prep_e, dim3(64),   dim3(256), 0, stream,
                       E, Esw, nE, idxPk, accum, done);
    hipLaunchKernelGGL(k_main,   dim3(512),  dim3(512), 0, stream,
                       Esw, nE, z, idxPk, nrmG);
    hipLaunchKernelGGL(k_epi,    dim3(2048), dim3(256), 0, stream,
                       idxPk, nrmG, E, accum, done, out);
}

// Round 12
// 126.266 us; speedup vs baseline: 1.4933x; 1.4933x over previous
//
#include <hip/hip_runtime.h>
#include <hip/hip_bf16.h>
#include <stdint.h>

// VQ-VAE vector quantizer forward, MI355X (gfx950).
// z: [32,256,32,32] fp32 (NCHW), E: [1024,256] fp32.
// score(n,k) = 0.5*||e_k||^2 - <f_n,e_k>  (argmin-equivalent to d2)
// dots via bf16 MFMA 16x16x32 fp32-accum; gather exact fp32.
//
// R17: R16 decomposition: k_main with (row-tile x code-half) grid = 512
// blocks, 2/CU, per-CU staged bytes constant -> k_main ~30us (vs 46 at
// 1 block/CU; phase skew across independent barrier domains fills the
// drain/A-prep stalls). R16's k_epi regression (8->87us) came from the
// 2048 per-block __threadfence + done atomics + atomicMin-produced
// lines. R17: winners via PLAIN stores to per-half arrays pkG[2][4096]
// (k_epi merges in-register -- same min compare, bit-identical);
// k_epi fence/done only in the 32 loss blocks; everything else pure
// gather/transpose/store.

typedef short v8s __attribute__((ext_vector_type(8)));
typedef float v4f __attribute__((ext_vector_type(4)));

__device__ inline unsigned short f2bf(float f) {  // RNE fp32->bf16
    uint32_t u = __float_as_uint(f);
    return (unsigned short)((u + 0x7fffu + ((u >> 16) & 1u)) >> 16);
}

// ---- Kernel 1: E -> SWIZZLED Ebf bf16 + nE + accum/done=0 ------------------
// Unit for (k, dc, g): U = (k>>4)*512 + dc*64 + g*16 + (k&15),
// holding elems d = dc*32 + g*8 .. +8. Coalesced 16B stores.
__global__ __launch_bounds__(256) void k_prep_e(const float* __restrict__ E,
                                                v8s* __restrict__ Esw,
                                                float* __restrict__ nE,
                                                float* __restrict__ accum,
                                                unsigned* __restrict__ done) {
    __shared__ float Ef[16][264];
    int q = blockIdx.x, tid = threadIdx.x;
    const float4* Ein = (const float4*)(E + ((size_t)q << 12));
#pragma unroll
    for (int i = 0; i < 4; i++) {
        int f4 = i * 256 + tid;
        int row = f4 >> 6, c4 = (f4 & 63) << 2;
        *(float4*)&Ef[row][c4] = Ein[f4];
    }
    __syncthreads();
    {
        int c = tid >> 4, l = tid & 15;
        float s = 0.f;
#pragma unroll
        for (int j = 0; j < 16; j++) { float v = Ef[c][l + 16 * j]; s += v * v; }
#pragma unroll
        for (int off = 1; off < 16; off <<= 1) s += __shfl_xor(s, off);
        if (l == 0) nE[q * 16 + c] = 0.5f * s;
    }
#pragma unroll
    for (int i = 0; i < 2; i++) {
        int u = tid + i * 256;
        int um = u & 15, ug = (u >> 4) & 3, udc = (u >> 6) & 7;
        int d0 = udc * 32 + ug * 8;
        union { v8s v; unsigned short s[8]; } pk;
#pragma unroll
        for (int e = 0; e < 8; e++) pk.s[e] = f2bf(Ef[um][d0 + e]);
        Esw[((size_t)q << 9) + u] = pk.v;
    }
    if (q == 0 && tid == 0) { accum[0] = 0.f; done[0] = 0u; }
}

// ---- Kernel 2: transpose+GEMM+argmin over a code-HALF; plain-store winners --
__global__ __launch_bounds__(512, 4) void k_main(
        const v8s* __restrict__ Esw,
        const float* __restrict__ nE,
        const float* __restrict__ z,
        unsigned long long* __restrict__ pkG,
        float* __restrict__ nrmG) {
    __shared__ v8s B[2][2048];      // 2 x 32 KB dbuf; A-tile (64 KB) overlays both
    __shared__ float nEl[512];

    int tid = threadIdx.x;
    int lane = tid & 63, w = tid >> 6;         // 8 waves
    int g = lane >> 4, m = lane & 15;          // MFMA lane coords
    int r_tile = blockIdx.x >> 1, h = blockIdx.x & 1;
    int R0 = r_tile << 7;                      // 128 rows/tile
    int b = R0 >> 10, hw0 = R0 & 1023;

    // ---- A-prep: z[b][0..256][hw0..hw0+128] -> swizzled bf16 tile @B -------
    // Thread (q=tid&31, dblk=tid>>5) loads 16 d-rows x float4 at hw quad 4q,
    // repacks to 8 v8s (4 rows x 2 slots). Swizzle slot^((row^row>>2)&7)
    // spreads both writes and fragment reads across all 8 bank-quads.
    {
        int q = tid & 31, dblk = tid >> 5;     // hw = hw0+4q, d base = dblk*16
        const float* zp = z + ((size_t)b << 18) + hw0 + (q << 2);
#pragma unroll
        for (int s = 0; s < 2; s++) {
            float4 L[8];
#pragma unroll
            for (int j = 0; j < 8; j++)
                L[j] = *(const float4*)(zp + (size_t)(((dblk << 4) + (s << 3) + j) << 10));
            const float* Lf = (const float*)L;
            int slot = (dblk << 1) + s;
#pragma unroll
            for (int c = 0; c < 4; c++) {
                union { v8s v; unsigned short u[8]; } pk;
#pragma unroll
                for (int j = 0; j < 8; j++) pk.u[j] = f2bf(Lf[j * 4 + c]);
                int row = (q << 2) + c;
                int sw = slot ^ ((row ^ (row >> 2)) & 7);
                *(v8s*)((char*)&B[0][0] + (row << 9) + (sw << 4)) = pk.v;
            }
        }
    }
    nEl[tid & 511] = nE[(h << 9) + (tid & 511)];
    __syncthreads();                           // A-tile + nEl resident

    // A frags: 16 rows/wave; row norm from the same bf16 values (h==0 writes).
    v8s a[8];
    {
        int row = (w << 4) + m;
        int f = (row ^ (row >> 2)) & 7;
#pragma unroll
        for (int dc = 0; dc < 8; dc++) {
            int sw = ((dc << 2) + g) ^ f;
            a[dc] = *(const v8s*)((const char*)&B[0][0] + (row << 9) + (sw << 4));
        }
        if (h == 0) {
            float nrm = 0.f;
#pragma unroll
            for (int dc = 0; dc < 8; dc++) {
                union { v8s v; unsigned short u[8]; } un; un.v = a[dc];
#pragma unroll
                for (int j = 0; j < 8; j++) {
                    float v = __uint_as_float((uint32_t)un.u[j] << 16);
                    nrm = fmaf(v, v, nrm);
                }
            }
            nrm += __shfl_xor(nrm, 16);        // reduce over g: full ||z_row||^2
            nrm += __shfl_xor(nrm, 32);
            if (g == 0) nrmG[R0 + row] = nrm;
        }
    }
    __syncthreads();                           // A consumed; B free for staging

    // staging: this half's chunk = 2048 v8s (32 KB); thread stages j*512+tid
#define STAGE(ch, buf)                                                        \
    {                                                                         \
        _Pragma("unroll")                                                     \
        for (int j = 0; j < 4; j++) {                                         \
            __builtin_amdgcn_global_load_lds(                                 \
                (const __attribute__((address_space(1))) void*)               \
                    (Esw + ((size_t)(h) << 14) + ((size_t)(ch) << 11)         \
                         + (j << 9) + (w << 6) + lane),                       \
                (__attribute__((address_space(3))) void*)                     \
                    &B[buf][(j << 9) + (w << 6)],                             \
                16, 0, 0);                                                    \
        }                                                                     \
    }

    float best[4]; int bidx[4];
#pragma unroll
    for (int r = 0; r < 4; r++) { best[r] = 3.4e38f; bidx[r] = 0; }

    STAGE(0, 0);
#pragma unroll 2
    for (int ct = 0; ct < 8; ct++) {
        int cur = ct & 1;                      // static after unroll 2
        __syncthreads();                       // chunk ct resident; reads done
        if (ct < 7) STAGE(ct + 1, cur ^ 1);
        float ne[4];
#pragma unroll
        for (int t = 0; t < 4; t++) ne[t] = nEl[(ct << 6) + (t << 4) + m];
        v4f acc[4];
#pragma unroll
        for (int t = 0; t < 4; t++) acc[t] = (v4f){0.f, 0.f, 0.f, 0.f};
#pragma unroll
        for (int dc = 0; dc < 8; dc++) {       // 4 indep chains/wave
#pragma unroll
            for (int t = 0; t < 4; t++) {
                v8s bf = B[cur][t * 512 + dc * 64 + g * 16 + m];
                acc[t] = __builtin_amdgcn_mfma_f32_16x16x32_bf16(a[dc], bf, acc[t], 0, 0, 0);
            }
        }
#pragma unroll
        for (int t = 0; t < 4; t++) {          // ascending code: tie -> low idx
            int code = (h << 9) + (ct << 6) + (t << 4) + m;
#pragma unroll
            for (int r = 0; r < 4; r++) {
                float s0 = ne[t] - acc[t][r];
                if (s0 < best[r]) { best[r] = s0; bidx[r] = code; }
            }
        }
    }

    // winner reduce over 16 code-columns (pack: min => low score, low code);
    // plain store to this half's slot -- k_epi merges the two halves.
#pragma unroll
    for (int r = 0; r < 4; r++) {
        uint32_t sb = __float_as_uint(best[r]);
        sb = (sb & 0x80000000u) ? ~sb : (sb | 0x80000000u);
        unsigned long long pk = ((unsigned long long)sb << 32) | (uint32_t)bidx[r];
#pragma unroll
        for (int off = 1; off < 16; off <<= 1) {
            unsigned long long o = __shfl_xor(pk, off);
            if (o < pk) pk = o;
        }
        if (m == 0) {                          // C/D row = g*4 + r
            int row = (w << 4) + (g << 2) + r;
            pkG[(h << 12) + R0 + row] = pk;
        }
    }
#undef STAGE
}

// ---- Kernel 3: merge halves + gather + NCHW write + loss + scalars ----------
// Block j owns (b = j>>6, d-quad d0 = (j&63)*4). Thread t: rows 4t..4t+3
// of batch b -> load both halves' packed winners, min-merge in register,
// 4x16B E-gathers (L2), register 4x4 transpose, 4 coalesced float4 row
// stores. Only the 32 blocks with (j&63)==0 fold the loss (2*s* + ||z||^2)
// and touch accum/fence/done; the last of them writes the 3 scalars.
__global__ __launch_bounds__(256) void k_epi(const unsigned long long* __restrict__ pkG,
                                             const float* __restrict__ nrmG,
                                             const float* __restrict__ E,
                                             float* __restrict__ accum,
                                             unsigned* __restrict__ done,
                                             float* __restrict__ out) {
    int j = blockIdx.x, t = threadIdx.x;
    int b = j >> 6, d0 = (j & 63) << 2;
    const unsigned long long* p0 = pkG + (b << 10) + (t << 2);          // h=0
    const unsigned long long* p1 = pkG + 4096 + (b << 10) + (t << 2);   // h=1
    unsigned long long mg[4];
#pragma unroll
    for (int i = 0; i < 4; i++) {
        unsigned long long a0 = p0[i], a1 = p1[i];
        mg[i] = a1 < a0 ? a1 : a0;
    }
    float4 e0 = *(const float4*)(E + ((size_t)(uint32_t)mg[0] << 8) + d0);
    float4 e1 = *(const float4*)(E + ((size_t)(uint32_t)mg[1] << 8) + d0);
    float4 e2 = *(const float4*)(E + ((size_t)(uint32_t)mg[2] << 8) + d0);
    float4 e3 = *(const float4*)(E + ((size_t)(uint32_t)mg[3] << 8) + d0);
    const float* q0 = &e0.x; const float* q1 = &e1.x;
    const float* q2 = &e2.x; const float* q3 = &e3.x;
    float* ob = out + ((size_t)b << 18) + ((size_t)d0 << 10) + (t << 2);
#pragma unroll
    for (int i = 0; i < 4; i++) {
        float4 v; v.x = q0[i]; v.y = q1[i]; v.z = q2[i]; v.w = q3[i];
        *(float4*)(ob + (size_t)i * 1024) = v;
    }
    if ((j & 63) == 0) {                       // loss for this batch's 1024 rows
        float4 nr = *(const float4*)(nrmG + (b << 10) + (t << 2));
        const float* nrp = &nr.x;
        float ls = 0.f;
#pragma unroll
        for (int i = 0; i < 4; i++) {
            uint32_t sc = (uint32_t)(mg[i] >> 32);
            float s = __uint_as_float((sc & 0x80000000u) ? (sc & 0x7fffffffu) : ~sc);
            ls += 2.0f * s + nrp[i];
        }
#pragma unroll
        for (int off = 1; off < 64; off <<= 1) ls += __shfl_xor(ls, off);
        __shared__ float w4[4];
        if ((t & 63) == 0) w4[t >> 6] = ls;
        __syncthreads();
        if (t == 0) {
            atomicAdd(accum, w4[0] + w4[1] + w4[2] + w4[3]);
            __threadfence();
            unsigned old = atomicAdd(done, 1u);
            if (old == 31u) {                  // all 32 loss blocks accumulated
                float s = atomicAdd(accum, 0.f) * (1.0f / 8388608.0f);
                out[8388608] = 1.25f * s;
                out[8388609] = s;
                out[8388610] = s;
            }
        }
    }
}

extern "C" void kernel_launch(void* const* d_in, const int* in_sizes, int n_in,
                              void* d_out, int out_size, void* d_ws, size_t ws_size,
                              hipStream_t stream) {
    const float* z = (const float*)d_in[0];
    const float* E = (const float*)d_in[1];
    char* ws = (char*)d_ws;
    v8s*                Esw   = (v8s*)(ws);                 // 524,288 B
    float*              nE    = (float*)(ws + 524288);      //   4,096 B
    float*              accum = (float*)(ws + 528384);      //       4 B
    unsigned*           done  = (unsigned*)(ws + 528388);   //       4 B
    float*              nrmG  = (float*)(ws + 528400);      // 131,072 B (16B-aligned)
    unsigned long long* pkG   = (unsigned long long*)(ws + 659472);  // 65,536 B
    float* out = (float*)d_out;

    hipLaunchKernelGGL(k_prep_e, dim3(64),   dim3(256), 0, stream,
                       E, Esw, nE, accum, done);
    hipLaunchKernelGGL(k_main,   dim3(512),  dim3(512), 0, stream,
                       Esw, nE, z, pkG, nrmG);
    hipLaunchKernelGGL(k_epi,    dim3(2048), dim3(256), 0, stream,
                       pkG, nrmG, E, accum, done, out);
}